// Round 14
// baseline (2761.672 us; speedup 1.0000x reference)
//
#include <hip/hip_runtime.h>
#include <math.h>

// ---- problem dims ----
#define B_    32
#define D_    384
#define DEPTH 24
#define DI    768
#define DS    16
#define DCONV 4
#define DTR   24
#define L_    197
#define NCLS  1000
#define NTOK  (B_*L_)   // 6304
#define MPAD  6400      // padded row count for GEMM A buffers
#define NXP   128       // padded x_proj output width (56 real: 24 dt-rank | 16 B | 16 C)
#define KDT   32        // padded dt_proj K (24 real)

typedef __bf16 bf16;
typedef __bf16 bf16x2 __attribute__((ext_vector_type(2)));
typedef __bf16 bf16x4 __attribute__((ext_vector_type(4)));
typedef __bf16 bf16x8 __attribute__((ext_vector_type(8)));
typedef float  floatx2 __attribute__((ext_vector_type(2)));
typedef float  floatx4 __attribute__((ext_vector_type(4)));

#define INW_E  (1536*384)
#define OUTW_E (384*768)
#define PW_E   (384*768)
#define HW_E   (1024*384)
#define XPW_E  (NXP*768)     // padded per-layer x_proj weight (rows 56..127 zero)
#define DTW_E  (768*KDT)     // padded per-layer dt_proj weight (cols 24..31 zero)

__device__ __forceinline__ float sigmoidf_(float x){ return 1.f/(1.f+__expf(-x)); }

// DPP-based lane exchange within 16-lane rows (keeps the LDS pipe free)
template<int CTRL>
__device__ __forceinline__ float dppf_(float x){
    return __int_as_float(__builtin_amdgcn_update_dpp(0, __float_as_int(x), CTRL, 0xF, 0xF, true));
}
template<int M>
__device__ __forceinline__ float sxor_(float x){
    if constexpr (M==1)      return dppf_<0xB1>(x);               // quad_perm [1,0,3,2]
    else if constexpr (M==2) return dppf_<0x4E>(x);               // quad_perm [2,3,0,1]
    else if constexpr (M==4) return dppf_<0x1B>(dppf_<0x141>(x)); // xor7 then xor3 = xor4
    else                     return dppf_<0x128>(x);              // row_ror:8 = xor8 (row=16)
}
template<int M>
__device__ __forceinline__ void rlevel_(float* v, const int s){
    const bool hi = (s & M) != 0;
    #pragma unroll
    for (int i = 0; i < M; ++i) {
        const float keep = hi ? v[i+M] : v[i];
        const float send = hi ? v[i] : v[i+M];
        v[i] = keep + sxor_<M>(send);
    }
}

// ---------------- all-weights fp32 -> bf16 conversion, 8 elems/thread ----------------
#define INW_ALL  ((long)DEPTH*INW_E)
#define OUTW_ALL ((long)DEPTH*OUTW_E)
#define XPW_ALL  ((long)DEPTH*XPW_E)
#define DTW_ALL  ((long)DEPTH*DTW_E)
#define SEG1 (INW_ALL)
#define SEG2 (SEG1 + OUTW_ALL)
#define SEG3 (SEG2 + PW_E)
#define SEG4 (SEG3 + HW_E)
#define SEG5 (SEG4 + XPW_ALL)
#define WCONV_TOT (SEG5 + DTW_ALL)
__global__ void wconv_all_kernel(const float* __restrict__ in_w, const float* __restrict__ out_w,
                                 const float* __restrict__ patch_w, const float* __restrict__ head_w,
                                 const float* __restrict__ xp_w, const float* __restrict__ dt_w,
                                 bf16* __restrict__ w_in_b, bf16* __restrict__ w_out_b,
                                 bf16* __restrict__ pw_b, bf16* __restrict__ hw_b,
                                 bf16* __restrict__ xpw_b, bf16* __restrict__ dtw_b)
{
    long idx = ((long)blockIdx.x*256 + threadIdx.x)*8;
    if (idx >= WCONV_TOT) return;
    const float* src; bf16* dst; long off;
    bool pad = false;
    if (idx < SEG1)       { src = in_w;  dst = w_in_b;  off = idx; }
    else if (idx < SEG2)  { src = out_w; dst = w_out_b; off = idx - SEG1; }
    else if (idx < SEG3)  { src = patch_w; dst = pw_b; off = idx - SEG2; }
    else if (idx < SEG4)  { off = idx - SEG3; src = head_w; dst = hw_b; pad = (off >= (long)NCLS*384); }
    else if (idx < SEG5)  {
        off = idx - SEG4; dst = xpw_b;
        const int layer = off / XPW_E; const int rem = off % XPW_E;
        const int r = rem / 768, c = rem % 768;
        pad = (r >= 56);
        src = xp_w + ((long)layer*56 + r)*768 + c - off;   // src+off == real element
    } else {
        off = idx - SEG5; dst = dtw_b;
        const int layer = off / DTW_E; const int rem = off % DTW_E;
        const int di = rem / KDT, c = rem % KDT;
        pad = (c >= 24);
        src = dt_w + ((long)layer*768 + di)*24 + c - off;
    }
    bf16x8 r;
    if (pad) {
        #pragma unroll
        for (int j = 0; j < 8; ++j) r[j] = (bf16)0.f;
    } else {
        const float4 a = *(const float4*)(src + off);
        const float4 c = *(const float4*)(src + off + 4);
        r[0]=(bf16)a.x; r[1]=(bf16)a.y; r[2]=(bf16)a.z; r[3]=(bf16)a.w;
        r[4]=(bf16)c.x; r[5]=(bf16)c.y; r[6]=(bf16)c.z; r[7]=(bf16)c.w;
    }
    *(bf16x8*)(dst + off) = r;
}

// ---------------- im2col: x[B,3,224,224] -> patches[b*197+1+pi, 768] bf16 ----------------
__global__ void im2col_kernel(const float* __restrict__ x, bf16* __restrict__ patches)
{
    const long idx = (long)blockIdx.x*256 + threadIdx.x;
    if (idx >= (long)B_*196*768) return;
    const int k = idx % 768;
    const int prow = idx / 768;
    const int b = prow / 196, pi = prow % 196;
    const int ph = pi / 14, pw = pi % 14;
    const int c = k >> 8, rem = k & 255, ii = rem >> 4, jj = rem & 15;
    patches[((long)(b*L_ + 1 + pi))*768 + k] =
        (bf16)x[(((long)b*3 + c)*224 + ph*16 + ii)*224 + pw*16 + jj];
}

// ---------------- tok = feat + pb + pos ; cls row = cls + pos ----------------
__global__ void add_pos_kernel(float* __restrict__ tok, const float* __restrict__ pb,
                               const float* __restrict__ pos, const float* __restrict__ cls)
{
    const int idx = blockIdx.x*256 + threadIdx.x;
    if (idx >= NTOK*D_) return;
    const int dd = idx % D_;
    const int row = idx / D_;
    const int p = row % L_;
    if (p == 0) tok[idx] = cls[dd] + pos[dd];
    else        tok[idx] += pb[dd] + pos[p*D_ + dd];
}

// ---------------- layernorm (per-layer LN and final norm) ----------------
template<typename OUT_T>
__global__ void ln_kernel(const float* __restrict__ x, const float* __restrict__ w,
                          const float* __restrict__ b, OUT_T* __restrict__ out,
                          int rows, int xstride, int ostride)
{
    const int row = blockIdx.x*blockDim.y + threadIdx.y;
    if (row >= rows) return;
    const int lane = threadIdx.x;
    const float* xr = x + (long)row*xstride;
    float v[6]; float s = 0.f;
    #pragma unroll
    for (int i = 0; i < 6; ++i) { v[i] = xr[lane + 64*i]; s += v[i]; }
    #pragma unroll
    for (int o = 32; o; o >>= 1) s += __shfl_xor(s, o, 64);
    const float mu = s * (1.f/384.f);
    float var = 0.f;
    #pragma unroll
    for (int i = 0; i < 6; ++i) { float d = v[i]-mu; var += d*d; }
    #pragma unroll
    for (int o = 32; o; o >>= 1) var += __shfl_xor(var, o, 64);
    const float rstd = rsqrtf(var*(1.f/384.f) + 1e-5f);
    OUT_T* orow = out + (long)row*ostride;
    #pragma unroll
    for (int i = 0; i < 6; ++i) { int c = lane + 64*i; orow[c] = (OUT_T)((v[i]-mu)*rstd*w[c] + b[c]); }
}

// ---------------- bf16 MFMA GEMM:  C[m,n] (+)= A[m,:K] . B[n,:K]  (B stored [N][K]) ----------------
// MODE: 0=store, (ACC=1)=accumulate, 1=softplus(acc+bias[col]), 2=head (out[row*NCLS+c]=acc+bias[c], c<NCLS)
template<int BM, int BN, int ACC, int MODE, typename CT>
__global__ __launch_bounds__(256)
void gemm_bf16_kernel(const bf16* __restrict__ A, const bf16* __restrict__ B,
                      CT* __restrict__ C, int M, int N, int K, int lda,
                      const float* __restrict__ bias)
{
    constexpr int ASLABS = BM/16;
    constexpr int BSLABS = BN/16;
    constexpr int NJ = (BM == 128) ? 4 : (BN/64);   // 128x128:4, 64x128:2, 64x64:1
    __shared__ bf16 As[BM*32];
    __shared__ bf16 Bs[BN*32];
    const int tid  = threadIdx.x;
    const int wave = tid >> 6, lane = tid & 63;
    const int bm = blockIdx.x*BM, bn = blockIdx.y*BN;
    const int wm = (BM == 128) ? (wave>>1)*64 : 0;
    const int wn = (BM == 128) ? (wave&1)*64 : wave*(NJ*16);
    floatx4 acc[4][NJ];
    #pragma unroll
    for (int i=0;i<4;++i)
        #pragma unroll
        for (int j=0;j<NJ;++j) acc[i][j] = (floatx4){0.f,0.f,0.f,0.f};

    const int lrow = lane >> 2;
    const int lcol = (lane & 3) * 8;
    const int am = lane & 15, ak = (lane>>4)*8;

    for (int k0 = 0; k0 < K; k0 += 32) {
        #pragma unroll
        for (int s = wave; s < ASLABS + BSLABS; s += 4) {
            if (s < ASLABS) {
                const bf16* ga = A + (long)(bm + s*16 + lrow)*lda + k0 + lcol;
                __builtin_amdgcn_global_load_lds(
                    (const __attribute__((address_space(1))) void*)ga,
                    (__attribute__((address_space(3))) void*)(As + s*512), 16, 0, 0);
            } else {
                const int s2 = s - ASLABS;
                const bf16* gb = B + (long)(bn + s2*16 + lrow)*K + k0 + lcol;
                __builtin_amdgcn_global_load_lds(
                    (const __attribute__((address_space(1))) void*)gb,
                    (__attribute__((address_space(3))) void*)(Bs + s2*512), 16, 0, 0);
            }
        }
        __syncthreads();
        bf16x8 af[4], bff[NJ];
        #pragma unroll
        for (int i=0;i<4;++i) af[i]  = *(const bf16x8*)(As + (wm + i*16 + am)*32 + ak);
        #pragma unroll
        for (int j=0;j<NJ;++j) bff[j] = *(const bf16x8*)(Bs + (wn + j*16 + am)*32 + ak);
        #pragma unroll
        for (int i=0;i<4;++i)
            #pragma unroll
            for (int j=0;j<NJ;++j)
                acc[i][j] = __builtin_amdgcn_mfma_f32_16x16x32_bf16(af[i], bff[j], acc[i][j], 0, 0, 0);
        __syncthreads();
    }
    const int rbase = bm + wm + (lane>>4)*4;
    const int cbase = bn + wn + (lane & 15);
    #pragma unroll
    for (int i = 0; i < 4; ++i) {
        #pragma unroll
        for (int r = 0; r < 4; ++r) {
            const int row = rbase + i*16 + r;
            if (row >= M) continue;
            #pragma unroll
            for (int j = 0; j < NJ; ++j) {
                const int c = cbase + j*16;
                const long idx = (long)row*N + c;
                if (MODE == 1) {
                    const float dr = acc[i][j][r] + bias[c];
                    const float dtv = (dr > 20.f) ? dr : __logf(1.f + __expf(dr));
                    C[idx] = (CT)dtv;
                } else if (MODE == 2) {
                    if (c < NCLS) C[(long)row*NCLS + c] = (CT)(acc[i][j][r] + bias[c]);
                } else if (ACC) {
                    C[idx] += acc[i][j][r];
                } else {
                    C[idx]  = (CT)acc[i][j][r];
                }
            }
        }
    }
}

// ---------------- fused x_proj + dt_proj (+bias+softplus), packed B/C output ----------------
// grid (NTOK/32). Phase 1: tmp32x64 = xbc[32 rows] @ xpw[0:64]^T; stash cols 0..31 (Ts) and
// cols 24..55 (Ts2, B|C) in LDS; repack Ts2 -> bc2[row][e] = (B,C) bf16x2 global.
// Phase 2: dtc[32 x 768] = Ts @ dtw^T (K=32), fused bias+softplus.
// dtw (48 KB) prefetched to LDS at kernel start; drains at first K-loop barrier.
// NOTE (round-11 lesson): conv must NOT be fused here (latency phase at 1 block/CU).
__global__ __launch_bounds__(256)
void xproj_dt_kernel(const bf16* __restrict__ xbc, const bf16* __restrict__ xpw,
                     const bf16* __restrict__ dtw, const float* __restrict__ bias,
                     bf16x2* __restrict__ bc2, bf16* __restrict__ dtc)
{
    __shared__ bf16 As[32*32];
    __shared__ bf16 Bs[64*32];
    __shared__ bf16 Ws[768*32];
    __shared__ bf16 Ts[32*32];
    __shared__ bf16 Ts2[32*32];
    const int tid  = threadIdx.x;
    const int wave = tid >> 6, lane = tid & 63;
    const int bm   = blockIdx.x*32;

    // prefetch dtw -> LDS (wave-uniform dest, per-lane 16B src); drains at first barrier
    #pragma unroll
    for (int it = 0; it < 12; ++it) {
        const int eoff = (it*4 + wave)*512;          // 512 bf16 = 1 KB per wave-chunk
        __builtin_amdgcn_global_load_lds(
            (const __attribute__((address_space(1))) void*)(dtw + eoff + lane*8),
            (__attribute__((address_space(3))) void*)(Ws + eoff), 16, 0, 0);
    }

    const int lrow = lane >> 2, lcol = (lane & 3)*8;
    const int am = lane & 15, ak = (lane >> 4)*8;
    const int wn = wave*16;

    floatx4 acc[2];
    acc[0] = (floatx4){0.f,0.f,0.f,0.f};
    acc[1] = (floatx4){0.f,0.f,0.f,0.f};

    for (int k0 = 0; k0 < 768; k0 += 32) {
        #pragma unroll
        for (int s = wave; s < 6; s += 4) {
            if (s < 2) {
                const bf16* ga = xbc + (long)(bm + s*16 + lrow)*DI + k0 + lcol;
                __builtin_amdgcn_global_load_lds(
                    (const __attribute__((address_space(1))) void*)ga,
                    (__attribute__((address_space(3))) void*)(As + s*512), 16, 0, 0);
            } else {
                const bf16* gb = xpw + (long)((s-2)*16 + lrow)*768 + k0 + lcol;
                __builtin_amdgcn_global_load_lds(
                    (const __attribute__((address_space(1))) void*)gb,
                    (__attribute__((address_space(3))) void*)(Bs + (s-2)*512), 16, 0, 0);
            }
        }
        __syncthreads();
        const bf16x8 af0 = *(const bf16x8*)(As + am*32 + ak);
        const bf16x8 af1 = *(const bf16x8*)(As + (16+am)*32 + ak);
        const bf16x8 bf  = *(const bf16x8*)(Bs + (wn+am)*32 + ak);
        acc[0] = __builtin_amdgcn_mfma_f32_16x16x32_bf16(af0, bf, acc[0], 0, 0, 0);
        acc[1] = __builtin_amdgcn_mfma_f32_16x16x32_bf16(af1, bf, acc[1], 0, 0, 0);
        __syncthreads();
    }

    // phase-1 epilogue: LDS stashes only (cols 0..31 -> Ts; cols 24..55 -> Ts2 as B|C)
    const int rb  = (lane>>4)*4;
    const int col = wn + (lane & 15);
    #pragma unroll
    for (int i = 0; i < 2; ++i) {
        #pragma unroll
        for (int r = 0; r < 4; ++r) {
            const int row = rb + i*16 + r;
            const bf16 v = (bf16)acc[i][r];
            if (wave < 2) Ts[row*32 + col] = v;
            if (col >= 24 && col < 56) Ts2[row*32 + col - 24] = v;
        }
    }
    __syncthreads();

    // bc2 repack: bc2[(bm+row)*16 + e] = (B[row][e], C[row][e]); 512 items, 2/thread
    #pragma unroll
    for (int i = 0; i < 2; ++i) {
        const int idx = tid + i*256;
        const int row = idx >> 4, e = idx & 15;
        bf16x2 bc; bc[0] = Ts2[row*32 + e]; bc[1] = Ts2[row*32 + 16 + e];
        bc2[(long)(bm + row)*16 + e] = bc;
    }

    // phase 2: 24 MFMAs/wave over dtw in LDS
    bf16x8 af2[2];
    af2[0] = *(const bf16x8*)(Ts + am*32 + ak);
    af2[1] = *(const bf16x8*)(Ts + (16+am)*32 + ak);
    #pragma unroll
    for (int jj = 0; jj < 12; ++jj) {
        const int ncol = wave*192 + jj*16;
        const bf16x8 bf2 = *(const bf16x8*)(Ws + (ncol+am)*32 + ak);
        const int ccol = ncol + (lane & 15);
        const float bv = bias[ccol];
        #pragma unroll
        for (int i = 0; i < 2; ++i) {
            const floatx4 a2 = __builtin_amdgcn_mfma_f32_16x16x32_bf16(
                af2[i], bf2, (floatx4){0.f,0.f,0.f,0.f}, 0, 0, 0);
            #pragma unroll
            for (int r = 0; r < 4; ++r) {
                const long row = bm + rb + i*16 + r;
                const float dr = a2[r] + bv;
                const float dtv = (dr > 20.f) ? dr : __logf(1.f + __expf(dr));
                dtc[row*DI + ccol] = (bf16)dtv;
            }
        }
    }
}

// ---------------- causal depthwise conv1d (DCONV=4) + bias + silu -> bf16, x8 vectorized ----------------
__global__ void conv_silu_kernel(const bf16* __restrict__ xz, const float* __restrict__ cw,
                                 const float* __restrict__ cb, bf16* __restrict__ out)
{
    const int idx = blockIdx.x*256 + threadIdx.x;      // over NTOK*96
    if (idx >= NTOK*96) return;
    const int g  = idx % 96;
    const int bl = idx / 96;
    const int l  = bl % L_;
    const int di = g*8;
    const long rowbase = (long)(bl - l)*(2*DI) + di;
    bf16x8 xv[4];
    #pragma unroll
    for (int k = 0; k < 4; ++k) {
        const int lt = l - 3 + k;
        if (lt >= 0) {
            xv[k] = *(const bf16x8*)(xz + rowbase + (long)lt*(2*DI));
        } else {
            #pragma unroll
            for (int j = 0; j < 8; ++j) xv[k][j] = (bf16)0.f;
        }
    }
    bf16x8 r;
    #pragma unroll
    for (int j = 0; j < 8; ++j) {
        const float4 wj = ((const float4*)cw)[di + j];
        float a = cb[di + j];
        a += wj.x*(float)xv[0][j] + wj.y*(float)xv[1][j] + wj.z*(float)xv[2][j] + wj.w*(float)xv[3][j];
        r[j] = (bf16)(a * sigmoidf_(a));
    }
    *(bf16x8*)(out + (long)bl*DI + di) = r;
}

// ---------------- barrier-free selective scan: T14 async-stage helpers ----------------
// LDS layout (f32, pair-major, 4 arrays x 5 KB = 20.5 KB):
//   arr[pair*32 + 2*e + (t&1)]  ->  floatx2 load at [g2*16 + idx] gives (val_t0, val_t1)
#define SCAN_PAIRS 40     // 80-token buffer = 40 token pairs
#define SCAN_ARR   (SCAN_PAIRS*32)
template<int NTK>
__device__ __forceinline__ void scan_ldpf(const bf16* __restrict__ xbc, const bf16* __restrict__ dtc,
                                          const bf16x2* __restrict__ bc2, long base, int t0,
                                          int di0, int e, int tid, bf16* pf)
{
    #pragma unroll
    for (int i = 0; i < NTK/16; ++i) {
        const int idx = tid + i*256;
        const int t = idx >> 4;
        const int gt_ = t0 + t;
        const int rt = (gt_ < L_) ? gt_ : (L_-1);     // clamp: always-valid load, zeroed at commit
        const long row = base + rt;
        pf[4*i+0] = xbc[row*DI + di0 + e];
        pf[4*i+1] = dtc[row*DI + di0 + e];            // softplus'd in xproj_dt
        *(bf16x2*)(pf + 4*i + 2) = bc2[row*16 + e];   // packed (B,C), 64 B contiguous per row
    }
}
template<int NTK>
__device__ __forceinline__ void scan_commit(float* __restrict__ sh_dt, float* __restrict__ sh_dx,
                                            float* __restrict__ sh_b, float* __restrict__ sh_c,
                                            int t0, int e, int tid, const bf16* pf)
{
    #pragma unroll
    for (int i = 0; i < NTK/16; ++i) {
        const int idx = tid + i*256;
        const int t = idx >> 4;
        const bool ok = (t0 + t) < L_;
        const int fi = (t >> 1)*32 + 2*e + (t & 1);
        const float xv  = ok ? (float)pf[4*i+0] : 0.f;
        const float dtv = ok ? (float)pf[4*i+1] : 0.f;
        sh_dt[fi] = dtv;
        sh_dx[fi] = dtv*xv;
        sh_b[fi]  = ok ? (float)pf[4*i+2] : 0.f;
        sh_c[fi]  = ok ? (float)pf[4*i+3] : 0.f;
    }
}
template<int NTK>
__device__ __forceinline__ float scan_compute(const float* __restrict__ sh_dt, const float* __restrict__ sh_dx,
                                              const float* __restrict__ sh_b, const float* __restrict__ sh_c,
                                              const bf16* __restrict__ xbc, const bf16* __restrict__ xz,
                                              bf16* __restrict__ y, long base, int t0,
                                              int dl, int s, int di, float A2_s, float Dv, float h)
{
    const floatx2* dtp = (const floatx2*)sh_dt;
    const floatx2* dxp = (const floatx2*)sh_dx;
    const floatx2* bp  = (const floatx2*)sh_b;
    const floatx2* cp  = (const floatx2*)sh_c;
    const floatx2 A2v = (floatx2){A2_s, A2_s};
    #pragma unroll
    for (int c = 0; c < NTK/16; ++c) {
        float v[16];
        #pragma unroll
        for (int t2 = 0; t2 < 8; ++t2) {
            const int g2 = c*8 + t2;
            const floatx2 dt2v = dtp[g2*16 + dl];   // (dt_t0, dt_t1)
            const floatx2 dx2  = dxp[g2*16 + dl];   // (dtx_t0, dtx_t1)
            const floatx2 b2   = bp[g2*16 + s];     // (B_t0, B_t1)
            const floatx2 c2   = cp[g2*16 + s];     // (C_t0, C_t1)
            const floatx2 ea = dt2v * A2v;          // v_pk_mul_f32
            const floatx2 m  = dx2 * b2;            // v_pk_mul_f32
            const float a0 = __builtin_amdgcn_exp2f(ea[0]);
            const float a1 = __builtin_amdgcn_exp2f(ea[1]);
            h = fmaf(a0, h, m[0]);
            const float h0 = h;
            h = fmaf(a1, h, m[1]);
            floatx2 vv; vv[0] = h0; vv[1] = h;
            vv = vv * c2;                           // v_pk_mul_f32
            v[2*t2]   = vv[0];
            v[2*t2+1] = vv[1];
        }
        const int gt = t0 + c*16 + s;
        const long row = base + gt;
        float xv = 0.f, zv = 0.f;
        if (gt < L_) {
            xv = (float)xbc[row*DI + di];
            zv = (float)xz[row*(2*DI) + DI + di];
        }
        rlevel_<8>(v, s); rlevel_<4>(v, s); rlevel_<2>(v, s); rlevel_<1>(v, s);
        if (gt < L_) {
            y[row*DI + di] = (bf16)((v[0] + Dv*xv) * zv * sigmoidf_(zv));
        }
    }
    return h;
}

// block 256 = 16 di x 16 s. grid (48, B_). 3-pass pair-major f32 LDS staging (80/64/64 tokens,
// 20.5 KB). T14 async-STAGE + packed-pair (v_pk_mul_f32) inner loop.
__global__ __launch_bounds__(256)
void scan_kernel(const bf16* __restrict__ xbc, const bf16* __restrict__ dtc,
                 const bf16x2* __restrict__ bc2, const bf16* __restrict__ xz,
                 const float* __restrict__ A_log, const float* __restrict__ Dp,
                 bf16* __restrict__ y)
{
    const int tid  = threadIdx.x;
    const int w    = tid >> 6, lane = tid & 63;
    const int s    = lane & 15;
    const int dlq  = lane >> 4;
    const int dl   = w*4 + dlq;
    const int bx   = blockIdx.x;
    const int cblk = (bx & 7)*6 + (bx >> 3);   // XCD-paired channel-block swizzle
    const int di0  = cblk*16;
    const int di   = di0 + dl;
    const int b    = blockIdx.y;

    const float A2_s = -__expf(A_log[di*DS + s]) * 1.44269504f;  // fold log2e -> exp2
    const float Dv   = Dp[di];

    __shared__ __align__(16) float sh[4*SCAN_ARR];   // dt | dtx | B | C, pair-major; 20.5 KB
    float* sh_dt = sh;
    float* sh_dx = sh + SCAN_ARR;
    float* sh_b  = sh + 2*SCAN_ARR;
    float* sh_c  = sh + 3*SCAN_ARR;

    const long base = (long)b*L_;
    const int e = tid & 15;

    bf16 pf[20];
    float h = 0.f;

    scan_ldpf<80>(xbc, dtc, bc2, base, 0, di0, e, tid, pf);
    scan_commit<80>(sh_dt, sh_dx, sh_b, sh_c, 0, e, tid, pf);
    __syncthreads();

    scan_ldpf<64>(xbc, dtc, bc2, base, 80, di0, e, tid, pf);
    h = scan_compute<80>(sh_dt, sh_dx, sh_b, sh_c, xbc, xz, y, base, 0, dl, s, di, A2_s, Dv, h);
    __syncthreads();
    scan_commit<64>(sh_dt, sh_dx, sh_b, sh_c, 80, e, tid, pf);
    __syncthreads();

    scan_ldpf<64>(xbc, dtc, bc2, base, 144, di0, e, tid, pf);
    h = scan_compute<64>(sh_dt, sh_dx, sh_b, sh_c, xbc, xz, y, base, 80, dl, s, di, A2_s, Dv, h);
    __syncthreads();
    scan_commit<64>(sh_dt, sh_dx, sh_b, sh_c, 144, e, tid, pf);
    __syncthreads();

    scan_compute<64>(sh_dt, sh_dx, sh_b, sh_c, xbc, xz, y, base, 144, dl, s, di, A2_s, Dv, h);
}

extern "C" void kernel_launch(void* const* d_in, const int* in_sizes, int n_in,
                              void* d_out, int out_size, void* d_ws, size_t ws_size,
                              hipStream_t stream)
{
    const float* x       = (const float*)d_in[0];
    const float* patch_w = (const float*)d_in[1];
    const float* patch_b = (const float*)d_in[2];
    const float* cls_tok = (const float*)d_in[3];
    const float* pos_emb = (const float*)d_in[4];
    const float* ln_w    = (const float*)d_in[5];
    const float* ln_b    = (const float*)d_in[6];
    const float* in_w    = (const float*)d_in[7];
    const float* conv_w  = (const float*)d_in[8];
    const float* conv_b  = (const float*)d_in[9];
    const float* xp_w    = (const float*)d_in[10];
    const float* dt_w    = (const float*)d_in[11];
    const float* dt_b    = (const float*)d_in[12];
    const float* A_log   = (const float*)d_in[13];
    const float* D_par   = (const float*)d_in[14];
    const float* out_w   = (const float*)d_in[15];
    const float* normf_w = (const float*)d_in[16];
    const float* normf_b = (const float*)d_in[17];
    const float* head_w  = (const float*)d_in[18];
    const float* head_b  = (const float*)d_in[19];
    float* out = (float*)d_out;

    // workspace layout (~109.1 MB, <= previously-working footprint)
    char* p = (char*)d_ws;
    float*  tok    = (float*)p;   p += (long)NTOK*D_*4;
    bf16*   xz_b   = (bf16*)p;    p += (long)MPAD*2*DI*2;
    bf16*   xbc_b  = (bf16*)p;    p += (long)MPAD*DI*2;
    bf16*   y_b    = (bf16*)p;    p += (long)MPAD*DI*2;
    bf16*   dtc_b  = (bf16*)p;    p += (long)MPAD*DI*2;     // softplus'd dt, stride 768
    bf16x2* bc2_b  = (bf16x2*)p;  p += (long)MPAD*16*4;     // packed (B,C) per (row, s)
    bf16*   ln0_b  = (bf16*)p;    p += (long)64*D_*2;
    bf16*   w_in_b = (bf16*)p;    p += (long)DEPTH*INW_E*2;
    bf16*   w_out_b= (bf16*)p;    p += (long)DEPTH*OUTW_E*2;
    bf16*   pw_b   = (bf16*)p;    p += (long)PW_E*2;
    bf16*   hw_b   = (bf16*)p;    p += (long)HW_E*2;
    bf16*   xpw_b  = (bf16*)p;    p += (long)DEPTH*XPW_E*2; // padded [128][768] per layer
    bf16*   dtw_b  = (bf16*)p;    p += (long)DEPTH*DTW_E*2; // padded [768][32] per layer
    bf16*   patches = dtc_b;      // pre-loop only (9.8 MB >= NTOK*768*2)
    bf16*   xnorm_b = y_b;        // xnorm live {ln -> in-GEMM}; y live {scan -> out-GEMM}: disjoint

    wconv_all_kernel<<<dim3((WCONV_TOT/8 + 255)/256), 256, 0, stream>>>(
        in_w, out_w, patch_w, head_w, xp_w, dt_w,
        w_in_b, w_out_b, pw_b, hw_b, xpw_b, dtw_b);

    im2col_kernel<<<dim3(((long)B_*196*768 + 255)/256), 256, 0, stream>>>(x, patches);
    gemm_bf16_kernel<64,64,0,0,float><<<dim3(100, 6), 256, 0, stream>>>(
        patches, pw_b, tok, NTOK, D_, 768, 768, nullptr);
    add_pos_kernel<<<dim3((NTOK*D_ + 255)/256), 256, 0, stream>>>(tok, patch_b, pos_emb, cls_tok);

    for (int layer = 0; layer < DEPTH; ++layer) {
        ln_kernel<bf16><<<dim3(NTOK/4), dim3(64,4), 0, stream>>>(
            tok, ln_w + layer*D_, ln_b + layer*D_, xnorm_b, NTOK, D_, D_);
        gemm_bf16_kernel<128,128,0,0,bf16><<<dim3(50, 12), 256, 0, stream>>>(
            xnorm_b, w_in_b + (long)layer*INW_E, xz_b, NTOK, 2*DI, D_, D_, nullptr);
        conv_silu_kernel<<<dim3((NTOK*96 + 255)/256), 256, 0, stream>>>(
            xz_b, conv_w + layer*DI*DCONV, conv_b + layer*DI, xbc_b);
        // fused x_proj + dt_proj (+bias+softplus), packed (B,C) output for scan staging
        xproj_dt_kernel<<<dim3(NTOK/32), 256, 0, stream>>>(
            xbc_b, xpw_b + (long)layer*XPW_E, dtw_b + (long)layer*DTW_E,
            dt_b + layer*DI, bc2_b, dtc_b);
        scan_kernel<<<dim3(48, B_), 256, 0, stream>>>(
            xbc_b, dtc_b, bc2_b, xz_b, A_log + layer*DI*DS, D_par + layer*DI, y_b);
        gemm_bf16_kernel<64,64,1,0,float><<<dim3(100, 6), 256, 0, stream>>>(
            y_b, w_out_b + (long)layer*OUTW_E, tok, NTOK, D_, DI, DI, nullptr);
    }

    ln_kernel<bf16><<<dim3(8), dim3(64,4), 0, stream>>>(tok, normf_w, normf_b, ln0_b, B_, L_*D_, D_);
    // head GEMM with fused bias, writing [32 x 1000] directly to out (MODE=2)
    gemm_bf16_kernel<64,128,0,2,float><<<dim3(1, 8), 256, 0, stream>>>(
        ln0_b, hw_b, out, B_, 1024, D_, D_, head_b);
}

// Round 15
// 2722.133 us; speedup vs baseline: 1.0145x; 1.0145x over previous
//
#include <hip/hip_runtime.h>
#include <math.h>

// ---- problem dims ----
#define B_    32
#define D_    384
#define DEPTH 24
#define DI    768
#define DS    16
#define DCONV 4
#define DTR   24
#define L_    197
#define NCLS  1000
#define NTOK  (B_*L_)   // 6304
#define MPAD  6400      // padded row count for GEMM A buffers
#define NXP   128       // padded x_proj output width (56 real: 24 dt-rank | 16 B | 16 C)
#define KDT   32        // padded dt_proj K (24 real)

typedef __bf16 bf16;
typedef __bf16 bf16x2 __attribute__((ext_vector_type(2)));
typedef __bf16 bf16x4 __attribute__((ext_vector_type(4)));
typedef __bf16 bf16x8 __attribute__((ext_vector_type(8)));
typedef float  floatx2 __attribute__((ext_vector_type(2)));
typedef float  floatx4 __attribute__((ext_vector_type(4)));

#define INW_E  (1536*384)
#define OUTW_E (384*768)
#define PW_E   (384*768)
#define HW_E   (1024*384)
#define XPW_E  (NXP*768)     // padded per-layer x_proj weight (rows 56..127 zero)
#define DTW_E  (768*KDT)     // padded per-layer dt_proj weight (cols 24..31 zero)

__device__ __forceinline__ float sigmoidf_(float x){ return 1.f/(1.f+__expf(-x)); }

// DPP-based lane exchange within 16-lane rows (keeps the LDS pipe free)
template<int CTRL>
__device__ __forceinline__ float dppf_(float x){
    return __int_as_float(__builtin_amdgcn_update_dpp(0, __float_as_int(x), CTRL, 0xF, 0xF, true));
}
template<int M>
__device__ __forceinline__ float sxor_(float x){
    if constexpr (M==1)      return dppf_<0xB1>(x);               // quad_perm [1,0,3,2]
    else if constexpr (M==2) return dppf_<0x4E>(x);               // quad_perm [2,3,0,1]
    else if constexpr (M==4) return dppf_<0x1B>(dppf_<0x141>(x)); // xor7 then xor3 = xor4
    else                     return dppf_<0x128>(x);              // row_ror:8 = xor8 (row=16)
}
template<int M>
__device__ __forceinline__ void rlevel_(float* v, const int s){
    const bool hi = (s & M) != 0;
    #pragma unroll
    for (int i = 0; i < M; ++i) {
        const float keep = hi ? v[i+M] : v[i];
        const float send = hi ? v[i] : v[i+M];
        v[i] = keep + sxor_<M>(send);
    }
}

// ---------------- all-weights fp32 -> bf16 conversion, 8 elems/thread ----------------
#define INW_ALL  ((long)DEPTH*INW_E)
#define OUTW_ALL ((long)DEPTH*OUTW_E)
#define XPW_ALL  ((long)DEPTH*XPW_E)
#define DTW_ALL  ((long)DEPTH*DTW_E)
#define SEG1 (INW_ALL)
#define SEG2 (SEG1 + OUTW_ALL)
#define SEG3 (SEG2 + PW_E)
#define SEG4 (SEG3 + HW_E)
#define SEG5 (SEG4 + XPW_ALL)
#define WCONV_TOT (SEG5 + DTW_ALL)
__global__ void wconv_all_kernel(const float* __restrict__ in_w, const float* __restrict__ out_w,
                                 const float* __restrict__ patch_w, const float* __restrict__ head_w,
                                 const float* __restrict__ xp_w, const float* __restrict__ dt_w,
                                 bf16* __restrict__ w_in_b, bf16* __restrict__ w_out_b,
                                 bf16* __restrict__ pw_b, bf16* __restrict__ hw_b,
                                 bf16* __restrict__ xpw_b, bf16* __restrict__ dtw_b)
{
    long idx = ((long)blockIdx.x*256 + threadIdx.x)*8;
    if (idx >= WCONV_TOT) return;
    const float* src; bf16* dst; long off;
    bool pad = false;
    if (idx < SEG1)       { src = in_w;  dst = w_in_b;  off = idx; }
    else if (idx < SEG2)  { src = out_w; dst = w_out_b; off = idx - SEG1; }
    else if (idx < SEG3)  { src = patch_w; dst = pw_b; off = idx - SEG2; }
    else if (idx < SEG4)  { off = idx - SEG3; src = head_w; dst = hw_b; pad = (off >= (long)NCLS*384); }
    else if (idx < SEG5)  {
        off = idx - SEG4; dst = xpw_b;
        const int layer = off / XPW_E; const int rem = off % XPW_E;
        const int r = rem / 768, c = rem % 768;
        pad = (r >= 56);
        src = xp_w + ((long)layer*56 + r)*768 + c - off;   // src+off == real element
    } else {
        off = idx - SEG5; dst = dtw_b;
        const int layer = off / DTW_E; const int rem = off % DTW_E;
        const int di = rem / KDT, c = rem % KDT;
        pad = (c >= 24);
        src = dt_w + ((long)layer*768 + di)*24 + c - off;
    }
    bf16x8 r;
    if (pad) {
        #pragma unroll
        for (int j = 0; j < 8; ++j) r[j] = (bf16)0.f;
    } else {
        const float4 a = *(const float4*)(src + off);
        const float4 c = *(const float4*)(src + off + 4);
        r[0]=(bf16)a.x; r[1]=(bf16)a.y; r[2]=(bf16)a.z; r[3]=(bf16)a.w;
        r[4]=(bf16)c.x; r[5]=(bf16)c.y; r[6]=(bf16)c.z; r[7]=(bf16)c.w;
    }
    *(bf16x8*)(dst + off) = r;
}

// ---------------- im2col: x[B,3,224,224] -> patches[b*197+1+pi, 768] bf16 ----------------
__global__ void im2col_kernel(const float* __restrict__ x, bf16* __restrict__ patches)
{
    const long idx = (long)blockIdx.x*256 + threadIdx.x;
    if (idx >= (long)B_*196*768) return;
    const int k = idx % 768;
    const int prow = idx / 768;
    const int b = prow / 196, pi = prow % 196;
    const int ph = pi / 14, pw = pi % 14;
    const int c = k >> 8, rem = k & 255, ii = rem >> 4, jj = rem & 15;
    patches[((long)(b*L_ + 1 + pi))*768 + k] =
        (bf16)x[(((long)b*3 + c)*224 + ph*16 + ii)*224 + pw*16 + jj];
}

// ---------------- tok = feat + pb + pos ; cls row = cls + pos ----------------
__global__ void add_pos_kernel(float* __restrict__ tok, const float* __restrict__ pb,
                               const float* __restrict__ pos, const float* __restrict__ cls)
{
    const int idx = blockIdx.x*256 + threadIdx.x;
    if (idx >= NTOK*D_) return;
    const int dd = idx % D_;
    const int row = idx / D_;
    const int p = row % L_;
    if (p == 0) tok[idx] = cls[dd] + pos[dd];
    else        tok[idx] += pb[dd] + pos[p*D_ + dd];
}

// ---------------- layernorm (per-layer LN and final norm) ----------------
template<typename OUT_T>
__global__ void ln_kernel(const float* __restrict__ x, const float* __restrict__ w,
                          const float* __restrict__ b, OUT_T* __restrict__ out,
                          int rows, int xstride, int ostride)
{
    const int row = blockIdx.x*blockDim.y + threadIdx.y;
    if (row >= rows) return;
    const int lane = threadIdx.x;
    const float* xr = x + (long)row*xstride;
    float v[6]; float s = 0.f;
    #pragma unroll
    for (int i = 0; i < 6; ++i) { v[i] = xr[lane + 64*i]; s += v[i]; }
    #pragma unroll
    for (int o = 32; o; o >>= 1) s += __shfl_xor(s, o, 64);
    const float mu = s * (1.f/384.f);
    float var = 0.f;
    #pragma unroll
    for (int i = 0; i < 6; ++i) { float d = v[i]-mu; var += d*d; }
    #pragma unroll
    for (int o = 32; o; o >>= 1) var += __shfl_xor(var, o, 64);
    const float rstd = rsqrtf(var*(1.f/384.f) + 1e-5f);
    OUT_T* orow = out + (long)row*ostride;
    #pragma unroll
    for (int i = 0; i < 6; ++i) { int c = lane + 64*i; orow[c] = (OUT_T)((v[i]-mu)*rstd*w[c] + b[c]); }
}

// ---------------- bf16 MFMA GEMM:  C[m,n] (+)= A[m,:K] . B[n,:K]  (B stored [N][K]) ----------------
// MODE: 0=store, (ACC=1)=accumulate, 1=softplus(acc+bias[col]), 2=head (out[row*NCLS+c]=acc+bias[c], c<NCLS)
template<int BM, int BN, int ACC, int MODE, typename CT>
__global__ __launch_bounds__(256)
void gemm_bf16_kernel(const bf16* __restrict__ A, const bf16* __restrict__ B,
                      CT* __restrict__ C, int M, int N, int K, int lda,
                      const float* __restrict__ bias)
{
    constexpr int ASLABS = BM/16;
    constexpr int BSLABS = BN/16;
    constexpr int NJ = (BM == 128) ? 4 : (BN/64);   // 128x128:4, 64x128:2, 64x64:1
    __shared__ bf16 As[BM*32];
    __shared__ bf16 Bs[BN*32];
    const int tid  = threadIdx.x;
    const int wave = tid >> 6, lane = tid & 63;
    const int bm = blockIdx.x*BM, bn = blockIdx.y*BN;
    const int wm = (BM == 128) ? (wave>>1)*64 : 0;
    const int wn = (BM == 128) ? (wave&1)*64 : wave*(NJ*16);
    floatx4 acc[4][NJ];
    #pragma unroll
    for (int i=0;i<4;++i)
        #pragma unroll
        for (int j=0;j<NJ;++j) acc[i][j] = (floatx4){0.f,0.f,0.f,0.f};

    const int lrow = lane >> 2;
    const int lcol = (lane & 3) * 8;
    const int am = lane & 15, ak = (lane>>4)*8;

    for (int k0 = 0; k0 < K; k0 += 32) {
        #pragma unroll
        for (int s = wave; s < ASLABS + BSLABS; s += 4) {
            if (s < ASLABS) {
                const bf16* ga = A + (long)(bm + s*16 + lrow)*lda + k0 + lcol;
                __builtin_amdgcn_global_load_lds(
                    (const __attribute__((address_space(1))) void*)ga,
                    (__attribute__((address_space(3))) void*)(As + s*512), 16, 0, 0);
            } else {
                const int s2 = s - ASLABS;
                const bf16* gb = B + (long)(bn + s2*16 + lrow)*K + k0 + lcol;
                __builtin_amdgcn_global_load_lds(
                    (const __attribute__((address_space(1))) void*)gb,
                    (__attribute__((address_space(3))) void*)(Bs + s2*512), 16, 0, 0);
            }
        }
        __syncthreads();
        bf16x8 af[4], bff[NJ];
        #pragma unroll
        for (int i=0;i<4;++i) af[i]  = *(const bf16x8*)(As + (wm + i*16 + am)*32 + ak);
        #pragma unroll
        for (int j=0;j<NJ;++j) bff[j] = *(const bf16x8*)(Bs + (wn + j*16 + am)*32 + ak);
        #pragma unroll
        for (int i=0;i<4;++i)
            #pragma unroll
            for (int j=0;j<NJ;++j)
                acc[i][j] = __builtin_amdgcn_mfma_f32_16x16x32_bf16(af[i], bff[j], acc[i][j], 0, 0, 0);
        __syncthreads();
    }
    const int rbase = bm + wm + (lane>>4)*4;
    const int cbase = bn + wn + (lane & 15);
    #pragma unroll
    for (int i = 0; i < 4; ++i) {
        #pragma unroll
        for (int r = 0; r < 4; ++r) {
            const int row = rbase + i*16 + r;
            if (row >= M) continue;
            #pragma unroll
            for (int j = 0; j < NJ; ++j) {
                const int c = cbase + j*16;
                const long idx = (long)row*N + c;
                if (MODE == 1) {
                    const float dr = acc[i][j][r] + bias[c];
                    const float dtv = (dr > 20.f) ? dr : __logf(1.f + __expf(dr));
                    C[idx] = (CT)dtv;
                } else if (MODE == 2) {
                    if (c < NCLS) C[(long)row*NCLS + c] = (CT)(acc[i][j][r] + bias[c]);
                } else if (ACC) {
                    C[idx] += acc[i][j][r];
                } else {
                    C[idx]  = (CT)acc[i][j][r];
                }
            }
        }
    }
}

// ---------------- fused x_proj + dt_proj (+bias+softplus), packed B/C output ----------------
// grid (NTOK/32). Phase 1: tmp32x64 = xbc[32 rows] @ xpw[0:64]^T; stash cols 0..31 (Ts) and
// cols 24..55 (Ts2, B|C) in LDS; repack Ts2 -> bc2[row][e] = (B,C) bf16x2 global.
// Phase 2: dtc[32 x 768] = Ts @ dtw^T (K=32), fused bias+softplus.
// dtw (48 KB) prefetched to LDS at kernel start; drains at first K-loop barrier.
// NOTE (round-11 lesson): conv must NOT be fused here (latency phase at 1 block/CU).
__global__ __launch_bounds__(256)
void xproj_dt_kernel(const bf16* __restrict__ xbc, const bf16* __restrict__ xpw,
                     const bf16* __restrict__ dtw, const float* __restrict__ bias,
                     bf16x2* __restrict__ bc2, bf16* __restrict__ dtc)
{
    __shared__ bf16 As[32*32];
    __shared__ bf16 Bs[64*32];
    __shared__ bf16 Ws[768*32];
    __shared__ bf16 Ts[32*32];
    __shared__ bf16 Ts2[32*32];
    const int tid  = threadIdx.x;
    const int wave = tid >> 6, lane = tid & 63;
    const int bm   = blockIdx.x*32;

    // prefetch dtw -> LDS (wave-uniform dest, per-lane 16B src); drains at first barrier
    #pragma unroll
    for (int it = 0; it < 12; ++it) {
        const int eoff = (it*4 + wave)*512;          // 512 bf16 = 1 KB per wave-chunk
        __builtin_amdgcn_global_load_lds(
            (const __attribute__((address_space(1))) void*)(dtw + eoff + lane*8),
            (__attribute__((address_space(3))) void*)(Ws + eoff), 16, 0, 0);
    }

    const int lrow = lane >> 2, lcol = (lane & 3)*8;
    const int am = lane & 15, ak = (lane >> 4)*8;
    const int wn = wave*16;

    floatx4 acc[2];
    acc[0] = (floatx4){0.f,0.f,0.f,0.f};
    acc[1] = (floatx4){0.f,0.f,0.f,0.f};

    for (int k0 = 0; k0 < 768; k0 += 32) {
        #pragma unroll
        for (int s = wave; s < 6; s += 4) {
            if (s < 2) {
                const bf16* ga = xbc + (long)(bm + s*16 + lrow)*DI + k0 + lcol;
                __builtin_amdgcn_global_load_lds(
                    (const __attribute__((address_space(1))) void*)ga,
                    (__attribute__((address_space(3))) void*)(As + s*512), 16, 0, 0);
            } else {
                const bf16* gb = xpw + (long)((s-2)*16 + lrow)*768 + k0 + lcol;
                __builtin_amdgcn_global_load_lds(
                    (const __attribute__((address_space(1))) void*)gb,
                    (__attribute__((address_space(3))) void*)(Bs + (s-2)*512), 16, 0, 0);
            }
        }
        __syncthreads();
        const bf16x8 af0 = *(const bf16x8*)(As + am*32 + ak);
        const bf16x8 af1 = *(const bf16x8*)(As + (16+am)*32 + ak);
        const bf16x8 bf  = *(const bf16x8*)(Bs + (wn+am)*32 + ak);
        acc[0] = __builtin_amdgcn_mfma_f32_16x16x32_bf16(af0, bf, acc[0], 0, 0, 0);
        acc[1] = __builtin_amdgcn_mfma_f32_16x16x32_bf16(af1, bf, acc[1], 0, 0, 0);
        __syncthreads();
    }

    // phase-1 epilogue: LDS stashes only (cols 0..31 -> Ts; cols 24..55 -> Ts2 as B|C)
    const int rb  = (lane>>4)*4;
    const int col = wn + (lane & 15);
    #pragma unroll
    for (int i = 0; i < 2; ++i) {
        #pragma unroll
        for (int r = 0; r < 4; ++r) {
            const int row = rb + i*16 + r;
            const bf16 v = (bf16)acc[i][r];
            if (wave < 2) Ts[row*32 + col] = v;
            if (col >= 24 && col < 56) Ts2[row*32 + col - 24] = v;
        }
    }
    __syncthreads();

    // bc2 repack: bc2[(bm+row)*16 + e] = (B[row][e], C[row][e]); 512 items, 2/thread
    #pragma unroll
    for (int i = 0; i < 2; ++i) {
        const int idx = tid + i*256;
        const int row = idx >> 4, e = idx & 15;
        bf16x2 bc; bc[0] = Ts2[row*32 + e]; bc[1] = Ts2[row*32 + 16 + e];
        bc2[(long)(bm + row)*16 + e] = bc;
    }

    // phase 2: 24 MFMAs/wave over dtw in LDS
    bf16x8 af2[2];
    af2[0] = *(const bf16x8*)(Ts + am*32 + ak);
    af2[1] = *(const bf16x8*)(Ts + (16+am)*32 + ak);
    #pragma unroll
    for (int jj = 0; jj < 12; ++jj) {
        const int ncol = wave*192 + jj*16;
        const bf16x8 bf2 = *(const bf16x8*)(Ws + (ncol+am)*32 + ak);
        const int ccol = ncol + (lane & 15);
        const float bv = bias[ccol];
        #pragma unroll
        for (int i = 0; i < 2; ++i) {
            const floatx4 a2 = __builtin_amdgcn_mfma_f32_16x16x32_bf16(
                af2[i], bf2, (floatx4){0.f,0.f,0.f,0.f}, 0, 0, 0);
            #pragma unroll
            for (int r = 0; r < 4; ++r) {
                const long row = bm + rb + i*16 + r;
                const float dr = a2[r] + bv;
                const float dtv = (dr > 20.f) ? dr : __logf(1.f + __expf(dr));
                dtc[row*DI + ccol] = (bf16)dtv;
            }
        }
    }
}

// ---------------- causal depthwise conv1d (DCONV=4) + bias + silu -> bf16, x8 vectorized ----------------
__global__ void conv_silu_kernel(const bf16* __restrict__ xz, const float* __restrict__ cw,
                                 const float* __restrict__ cb, bf16* __restrict__ out)
{
    const int idx = blockIdx.x*256 + threadIdx.x;      // over NTOK*96
    if (idx >= NTOK*96) return;
    const int g  = idx % 96;
    const int bl = idx / 96;
    const int l  = bl % L_;
    const int di = g*8;
    const long rowbase = (long)(bl - l)*(2*DI) + di;
    bf16x8 xv[4];
    #pragma unroll
    for (int k = 0; k < 4; ++k) {
        const int lt = l - 3 + k;
        if (lt >= 0) {
            xv[k] = *(const bf16x8*)(xz + rowbase + (long)lt*(2*DI));
        } else {
            #pragma unroll
            for (int j = 0; j < 8; ++j) xv[k][j] = (bf16)0.f;
        }
    }
    bf16x8 r;
    #pragma unroll
    for (int j = 0; j < 8; ++j) {
        const float4 wj = ((const float4*)cw)[di + j];
        float a = cb[di + j];
        a += wj.x*(float)xv[0][j] + wj.y*(float)xv[1][j] + wj.z*(float)xv[2][j] + wj.w*(float)xv[3][j];
        r[j] = (bf16)(a * sigmoidf_(a));
    }
    *(bf16x8*)(out + (long)bl*DI + di) = r;
}

// ---------------- barrier-free selective scan: T14 async-stage helpers ----------------
template<int NTK>
__device__ __forceinline__ void scan_ldpf(const bf16* __restrict__ xbc, const bf16* __restrict__ dtc,
                                          const bf16x2* __restrict__ bc2, long base, int t0,
                                          int di0, int e, int tid, bf16* pf)
{
    #pragma unroll
    for (int i = 0; i < NTK/16; ++i) {
        const int idx = tid + i*256;
        const int t = idx >> 4;
        const int gt_ = t0 + t;
        const int rt = (gt_ < L_) ? gt_ : (L_-1);     // clamp: always-valid load, zeroed at commit
        const long row = base + rt;
        pf[4*i+0] = xbc[row*DI + di0 + e];
        pf[4*i+1] = dtc[row*DI + di0 + e];            // softplus'd in xproj_dt
        *(bf16x2*)(pf + 4*i + 2) = bc2[row*16 + e];   // packed (B,C), 64 B contiguous per row
    }
}
template<int NTK>
__device__ __forceinline__ void scan_commit(floatx2* __restrict__ sh_dtf, floatx2* __restrict__ sh_bcf,
                                            int t0, int e, int tid, const bf16* pf)
{
    #pragma unroll
    for (int i = 0; i < NTK/16; ++i) {
        const int idx = tid + i*256;
        const int t = idx >> 4;
        const bool ok = (t0 + t) < L_;
        const int idx2 = (t >> 1)*32 + 2*e + (t & 1);
        const float xv  = ok ? (float)pf[4*i+0] : 0.f;
        const float dtv = ok ? (float)pf[4*i+1] : 0.f;
        floatx2 dtdx; dtdx[0] = dtv; dtdx[1] = dtv*xv;
        floatx2 bc;   bc[0] = ok ? (float)pf[4*i+2] : 0.f;
        bc[1] = ok ? (float)pf[4*i+3] : 0.f;
        sh_dtf[idx2] = dtdx;
        sh_bcf[idx2] = bc;
    }
}
template<int NTK>
__device__ __forceinline__ float scan_compute(const floatx2* __restrict__ sh_dtf,
                                              const floatx2* __restrict__ sh_bcf,
                                              const bf16* __restrict__ xbc, const bf16* __restrict__ xz,
                                              bf16* __restrict__ y, long base, int t0,
                                              int dl, int s, int di, float A2_s, float Dv, float h)
{
    const floatx4* dt4 = (const floatx4*)sh_dtf;
    const floatx4* bc4 = (const floatx4*)sh_bcf;
    #pragma unroll
    for (int c = 0; c < NTK/16; ++c) {
        float v[16];
        #pragma unroll
        for (int t2 = 0; t2 < 8; ++t2) {
            const int g2 = c*8 + t2;
            const floatx4 q  = dt4[g2*16 + dl];   // dt_t0, dtx_t0, dt_t1, dtx_t1
            const floatx4 bc = bc4[g2*16 + s];    // B_t0, C_t0, B_t1, C_t1
            const float a0 = __builtin_amdgcn_exp2f(q[0] * A2_s);
            h = fmaf(a0, h, q[1] * bc[0]);
            v[2*t2]   = h * bc[1];
            const float a1 = __builtin_amdgcn_exp2f(q[2] * A2_s);
            h = fmaf(a1, h, q[3] * bc[2]);
            v[2*t2+1] = h * bc[3];
        }
        const int gt = t0 + c*16 + s;
        const long row = base + gt;
        float xv = 0.f, zv = 0.f;
        if (gt < L_) {
            xv = (float)xbc[row*DI + di];
            zv = (float)xz[row*(2*DI) + DI + di];
        }
        rlevel_<8>(v, s); rlevel_<4>(v, s); rlevel_<2>(v, s); rlevel_<1>(v, s);
        if (gt < L_) {
            y[row*DI + di] = (bf16)((v[0] + Dv*xv) * zv * sigmoidf_(zv));
        }
    }
    return h;
}

// block 256 = 16 di x 16 s. grid (48, B_). 3-pass f32 LDS staging (80/64/64 tokens, 20.5 KB).
// T14 async-STAGE: pass p+1's global loads issued to regs BEFORE pass p's compute.
__global__ __launch_bounds__(256)
void scan_kernel(const bf16* __restrict__ xbc, const bf16* __restrict__ dtc,
                 const bf16x2* __restrict__ bc2, const bf16* __restrict__ xz,
                 const float* __restrict__ A_log, const float* __restrict__ Dp,
                 bf16* __restrict__ y)
{
    const int tid  = threadIdx.x;
    const int w    = tid >> 6, lane = tid & 63;
    const int s    = lane & 15;
    const int dlq  = lane >> 4;
    const int dl   = w*4 + dlq;
    const int bx   = blockIdx.x;
    const int cblk = (bx & 7)*6 + (bx >> 3);   // XCD-paired channel-block swizzle
    const int di0  = cblk*16;
    const int di   = di0 + dl;
    const int b    = blockIdx.y;

    const float A2_s = -__expf(A_log[di*DS + s]) * 1.44269504f;  // fold log2e -> exp2
    const float Dv   = Dp[di];

    __shared__ __align__(16) floatx2 sh_dtf[80*16];  // (dt,dtx) per (t,dl); 10 KB
    __shared__ __align__(16) floatx2 sh_bcf[80*16];  // (B,C)   per (t,s);  10 KB

    const long base = (long)b*L_;
    const int e = tid & 15;

    bf16 pf[20];
    float h = 0.f;

    scan_ldpf<80>(xbc, dtc, bc2, base, 0, di0, e, tid, pf);
    scan_commit<80>(sh_dtf, sh_bcf, 0, e, tid, pf);
    __syncthreads();

    scan_ldpf<64>(xbc, dtc, bc2, base, 80, di0, e, tid, pf);
    h = scan_compute<80>(sh_dtf, sh_bcf, xbc, xz, y, base, 0, dl, s, di, A2_s, Dv, h);
    __syncthreads();
    scan_commit<64>(sh_dtf, sh_bcf, 80, e, tid, pf);
    __syncthreads();

    scan_ldpf<64>(xbc, dtc, bc2, base, 144, di0, e, tid, pf);
    h = scan_compute<64>(sh_dtf, sh_bcf, xbc, xz, y, base, 80, dl, s, di, A2_s, Dv, h);
    __syncthreads();
    scan_commit<64>(sh_dtf, sh_bcf, 144, e, tid, pf);
    __syncthreads();

    scan_compute<64>(sh_dtf, sh_bcf, xbc, xz, y, base, 144, dl, s, di, A2_s, Dv, h);
}

extern "C" void kernel_launch(void* const* d_in, const int* in_sizes, int n_in,
                              void* d_out, int out_size, void* d_ws, size_t ws_size,
                              hipStream_t stream)
{
    const float* x       = (const float*)d_in[0];
    const float* patch_w = (const float*)d_in[1];
    const float* patch_b = (const float*)d_in[2];
    const float* cls_tok = (const float*)d_in[3];
    const float* pos_emb = (const float*)d_in[4];
    const float* ln_w    = (const float*)d_in[5];
    const float* ln_b    = (const float*)d_in[6];
    const float* in_w    = (const float*)d_in[7];
    const float* conv_w  = (const float*)d_in[8];
    const float* conv_b  = (const float*)d_in[9];
    const float* xp_w    = (const float*)d_in[10];
    const float* dt_w    = (const float*)d_in[11];
    const float* dt_b    = (const float*)d_in[12];
    const float* A_log   = (const float*)d_in[13];
    const float* D_par   = (const float*)d_in[14];
    const float* out_w   = (const float*)d_in[15];
    const float* normf_w = (const float*)d_in[16];
    const float* normf_b = (const float*)d_in[17];
    const float* head_w  = (const float*)d_in[18];
    const float* head_b  = (const float*)d_in[19];
    float* out = (float*)d_out;

    // workspace layout (~109.1 MB, <= previously-working footprint)
    char* p = (char*)d_ws;
    float*  tok    = (float*)p;   p += (long)NTOK*D_*4;
    bf16*   xz_b   = (bf16*)p;    p += (long)MPAD*2*DI*2;
    bf16*   xbc_b  = (bf16*)p;    p += (long)MPAD*DI*2;
    bf16*   y_b    = (bf16*)p;    p += (long)MPAD*DI*2;
    bf16*   dtc_b  = (bf16*)p;    p += (long)MPAD*DI*2;     // softplus'd dt, stride 768
    bf16x2* bc2_b  = (bf16x2*)p;  p += (long)MPAD*16*4;     // packed (B,C) per (row, s)
    bf16*   ln0_b  = (bf16*)p;    p += (long)64*D_*2;
    bf16*   w_in_b = (bf16*)p;    p += (long)DEPTH*INW_E*2;
    bf16*   w_out_b= (bf16*)p;    p += (long)DEPTH*OUTW_E*2;
    bf16*   pw_b   = (bf16*)p;    p += (long)PW_E*2;
    bf16*   hw_b   = (bf16*)p;    p += (long)HW_E*2;
    bf16*   xpw_b  = (bf16*)p;    p += (long)DEPTH*XPW_E*2; // padded [128][768] per layer
    bf16*   dtw_b  = (bf16*)p;    p += (long)DEPTH*DTW_E*2; // padded [768][32] per layer
    bf16*   patches = dtc_b;      // pre-loop only (9.8 MB >= NTOK*768*2)
    bf16*   xnorm_b = y_b;        // xnorm live {ln -> in-GEMM}; y live {scan -> out-GEMM}: disjoint

    wconv_all_kernel<<<dim3((WCONV_TOT/8 + 255)/256), 256, 0, stream>>>(
        in_w, out_w, patch_w, head_w, xp_w, dt_w,
        w_in_b, w_out_b, pw_b, hw_b, xpw_b, dtw_b);

    im2col_kernel<<<dim3(((long)B_*196*768 + 255)/256), 256, 0, stream>>>(x, patches);
    gemm_bf16_kernel<64,64,0,0,float><<<dim3(100, 6), 256, 0, stream>>>(
        patches, pw_b, tok, NTOK, D_, 768, 768, nullptr);
    add_pos_kernel<<<dim3((NTOK*D_ + 255)/256), 256, 0, stream>>>(tok, patch_b, pos_emb, cls_tok);

    for (int layer = 0; layer < DEPTH; ++layer) {
        ln_kernel<bf16><<<dim3(NTOK/4), dim3(64,4), 0, stream>>>(
            tok, ln_w + layer*D_, ln_b + layer*D_, xnorm_b, NTOK, D_, D_);
        gemm_bf16_kernel<128,128,0,0,bf16><<<dim3(50, 12), 256, 0, stream>>>(
            xnorm_b, w_in_b + (long)layer*INW_E, xz_b, NTOK, 2*DI, D_, D_, nullptr);
        conv_silu_kernel<<<dim3((NTOK*96 + 255)/256), 256, 0, stream>>>(
            xz_b, conv_w + layer*DI*DCONV, conv_b + layer*DI, xbc_b);
        // fused x_proj + dt_proj (+bias+softplus), packed (B,C) output for scan staging
        xproj_dt_kernel<<<dim3(NTOK/32), 256, 0, stream>>>(
            xbc_b, xpw_b + (long)layer*XPW_E, dtw_b + (long)layer*DTW_E,
            dt_b + layer*DI, bc2_b, dtc_b);
        scan_kernel<<<dim3(48, B_), 256, 0, stream>>>(
            xbc_b, dtc_b, bc2_b, xz_b, A_log + layer*DI*DS, D_par + layer*DI, y_b);
        gemm_bf16_kernel<64,64,1,0,float><<<dim3(100, 6), 256, 0, stream>>>(
            y_b, w_out_b + (long)layer*OUTW_E, tok, NTOK, D_, DI, DI, nullptr);
    }

    ln_kernel<bf16><<<dim3(8), dim3(64,4), 0, stream>>>(tok, normf_w, normf_b, ln0_b, B_, L_*D_, D_);
    // head GEMM with fused bias, writing [32 x 1000] directly to out (MODE=2)
    gemm_bf16_kernel<64,128,0,2,float><<<dim3(1, 8), 256, 0, stream>>>(
        ln0_b, hw_b, out, B_, 1024, D_, D_, head_b);
}